// Round 1
// baseline (192.371 us; speedup 1.0000x reference)
//
#include <hip/hip_runtime.h>
#include <hip/hip_bf16.h>
#include <stdint.h>

#define SEQ 2048
#define HD  128
#define WIN 512
#define NH  16
#define NKV 4
#define BATCH 2

typedef __attribute__((ext_vector_type(8))) short bf16x8;
typedef __attribute__((ext_vector_type(4))) short bf16x4;
typedef __attribute__((ext_vector_type(4))) float f32x4;

// v_exp_f32: D = 2^S0 — avoids the glibc __exp2f macro collision
#define EXP2(x) __builtin_amdgcn_exp2f(x)

// LDS row strides in bf16 elements (byte-strides multiples of 16B for b128)
#define KSTR 136   // K tile  [64 keys][128 dims]
#define VSTR 72    // V^T tile [128 dims][64 keys]

__device__ __forceinline__ uint32_t pk2(float a, float b) {
    __hip_bfloat162 h = __float22bfloat162_rn(make_float2(a, b));
    return *reinterpret_cast<uint32_t*>(&h);
}

// K=16 MFMA: A-operand layout (row=lane&15, k=(lane>>4)*4+j) matches the
// 16x16 C-layout of S^T exactly -> P feeds PV directly from registers.
__device__ __forceinline__ f32x4 mfma16(bf16x4 a, bf16x4 b, f32x4 c) {
#if __has_builtin(__builtin_amdgcn_mfma_f32_16x16x16bf16_1k)
    return __builtin_amdgcn_mfma_f32_16x16x16bf16_1k(a, b, c, 0, 0, 0);
#else
    // fallback: raw ISA op; conservative nops protect the D-read hazard
    asm volatile("v_mfma_f32_16x16x16_bf16 %0, %1, %2, %0\n\ts_nop 7\n\ts_nop 7"
                 : "+v"(c) : "v"(a), "v"(b));
    return c;
#endif
}

// 4 waves/block, 32 queries/wave. S^T = K·Q^T so softmax stats are per-column
// (q = lane&15). K/V double-buffered in LDS -> single barrier per tile;
// tile kt+1's global loads issued before tile kt's compute, packed to the
// other buffer mid-compute. P never touches LDS (16x16x16 PV from registers).
__global__ __launch_bounds__(256, 2) void fa_mfma(
    const float* __restrict__ q,
    const float* __restrict__ k,
    const float* __restrict__ v,
    float* __restrict__ out)
{
    const int tid  = threadIdx.x;
    const int wave = tid >> 6;
    const int lane = tid & 63;
    const int l4   = lane >> 4;
    const int l15  = lane & 15;

    const int bh   = blockIdx.x >> 4;      // b*NH + h
    const int qblk = blockIdx.x & 15;
    const int q0   = qblk << 7;            // 128 queries per block
    const int hkv  = (bh & (NH - 1)) >> 2; // G = 4
    const int b    = bh >> 4;

    const int i0   = q0 + wave * 32;       // wave's first query row

    __shared__ __align__(16) uint16_t lds_k[2][64 * KSTR];
    __shared__ __align__(16) uint16_t lds_vt[2][HD * VSTR];

    // scale * log2(e): softmax computed in exp2 domain
    const float scale2 = 0.08838834764831845f * 1.4426950408889634f;

    const size_t qbase  = (size_t)bh * SEQ * HD;
    const size_t kvbase = (size_t)(b * NKV + hkv) * SEQ * HD;

    // ---- preload Q fragments (B-operand: B[k=dim][n=q]) ----
    union { bf16x8 f; uint32_t u[4]; } qf[2][4];
    #pragma unroll
    for (int nt = 0; nt < 2; ++nt) {
        const float* qr = q + qbase + (size_t)(i0 + nt * 16 + l15) * HD;
        #pragma unroll
        for (int ks = 0; ks < 4; ++ks) {
            const float4* g = reinterpret_cast<const float4*>(qr + ks * 32 + l4 * 8);
            float4 a = g[0], bq = g[1];
            qf[nt][ks].u[0] = pk2(a.x * scale2, a.y * scale2);
            qf[nt][ks].u[1] = pk2(a.z * scale2, a.w * scale2);
            qf[nt][ks].u[2] = pk2(bq.x * scale2, bq.y * scale2);
            qf[nt][ks].u[3] = pk2(bq.z * scale2, bq.w * scale2);
        }
    }

    f32x4 O[2][8];
    #pragma unroll
    for (int a1 = 0; a1 < 2; ++a1)
        #pragma unroll
        for (int a2 = 0; a2 < 8; ++a2) O[a1][a2] = (f32x4){0.f, 0.f, 0.f, 0.f};
    float mrow[2] = {-1e30f, -1e30f};
    float lrow[2] = {0.f, 0.f};

    const int kt_lo_blk = (q0 >= 512) ? ((q0 - 511) >> 6) : 0;
    const int kt_hi_blk = (q0 + 127) >> 6;
    const int lo_w = (i0 >= 512) ? ((i0 - 511) >> 6) : 0;
    const int hi_w = (i0 + 31) >> 6;

    // ---- prefetch registers ----
    const int vdg = tid & 31;   // dim group (4 dims)
    const int vkg = tid >> 5;   // key group (8 keys)
    float4 rKa[4], rKb[4], rV[8];

    auto prefetch = [&](int kt) {
        const float* kp = k + kvbase + (size_t)kt * 64 * HD;
        const float* vp = v + kvbase + (size_t)kt * 64 * HD;
        #pragma unroll
        for (int it = 0; it < 4; ++it) {
            int flat8 = tid + it * 256, key = flat8 >> 4, ch = flat8 & 15;
            const float4* g = reinterpret_cast<const float4*>(kp + key * HD + ch * 8);
            rKa[it] = g[0]; rKb[it] = g[1];
        }
        #pragma unroll
        for (int r = 0; r < 8; ++r)
            rV[r] = *reinterpret_cast<const float4*>(vp + (vkg * 8 + r) * HD + vdg * 4);
    };

    auto pack = [&](int pb) {
        // K tile -> LDS (b128 writes)
        #pragma unroll
        for (int it = 0; it < 4; ++it) {
            int flat8 = tid + it * 256, key = flat8 >> 4, ch = flat8 & 15;
            uint4 wv;
            wv.x = pk2(rKa[it].x, rKa[it].y);  wv.y = pk2(rKa[it].z, rKa[it].w);
            wv.z = pk2(rKb[it].x, rKb[it].y);  wv.w = pk2(rKb[it].z, rKb[it].w);
            *reinterpret_cast<uint4*>(&lds_k[pb][key * KSTR + ch * 8]) = wv;
        }
        // V (register 8x4 transpose) -> LDS
        const float* rvf = reinterpret_cast<const float*>(rV);
        #pragma unroll
        for (int i = 0; i < 4; ++i) {
            uint4 wv;
            wv.x = pk2(rvf[0 * 4 + i], rvf[1 * 4 + i]);
            wv.y = pk2(rvf[2 * 4 + i], rvf[3 * 4 + i]);
            wv.z = pk2(rvf[4 * 4 + i], rvf[5 * 4 + i]);
            wv.w = pk2(rvf[6 * 4 + i], rvf[7 * 4 + i]);
            *reinterpret_cast<uint4*>(&lds_vt[pb][(vdg * 4 + i) * VSTR + vkg * 8]) = wv;
        }
    };

    prefetch(kt_lo_blk);
    pack(0);
    __syncthreads();

    int par = 0;
    for (int kt = kt_lo_blk; kt <= kt_hi_blk; ++kt) {
        const bool more = (kt < kt_hi_blk);
        if (more) prefetch(kt + 1);   // issue next tile's global loads early

        if (kt >= lo_w && kt <= hi_w) {
            // ---------- S^T = K · Q^T ----------
            f32x4 sf[4][2];
            #pragma unroll
            for (int mt = 0; mt < 4; ++mt) {
                #pragma unroll
                for (int nt = 0; nt < 2; ++nt) sf[mt][nt] = (f32x4){0.f, 0.f, 0.f, 0.f};
                #pragma unroll
                for (int ks = 0; ks < 4; ++ks) {
                    bf16x8 af = *reinterpret_cast<const bf16x8*>(
                        &lds_k[par][(mt * 16 + l15) * KSTR + ks * 32 + l4 * 8]);
                    #pragma unroll
                    for (int nt = 0; nt < 2; ++nt)
                        sf[mt][nt] = __builtin_amdgcn_mfma_f32_16x16x32_bf16(
                            af, qf[nt][ks].f, sf[mt][nt], 0, 0, 0);
                }
            }
            // ---------- mask (first/window and last/causal tiles only) ------
            const bool needmask = (kt == hi_w) || (kt == lo_w && i0 > 511);
            if (needmask) {
                #pragma unroll
                for (int mt = 0; mt < 4; ++mt) {
                    int jb = kt * 64 + mt * 16 + l4 * 4;
                    #pragma unroll
                    for (int nt = 0; nt < 2; ++nt) {
                        int iq = i0 + nt * 16 + l15;
                        #pragma unroll
                        for (int r = 0; r < 4; ++r) {
                            int j = jb + r;
                            if (!((j <= iq) && (iq - j < WIN))) sf[mt][nt][r] = -1e30f;
                        }
                    }
                }
            }
            // ---------- online softmax, exp2 domain, defer-max (THR=8) ------
            float tm[2];
            #pragma unroll
            for (int nt = 0; nt < 2; ++nt) {
                float a0 = fmaxf(fmaxf(sf[0][nt][0], sf[0][nt][1]),
                                 fmaxf(sf[0][nt][2], sf[0][nt][3]));
                float a1 = fmaxf(fmaxf(sf[1][nt][0], sf[1][nt][1]),
                                 fmaxf(sf[1][nt][2], sf[1][nt][3]));
                float a2 = fmaxf(fmaxf(sf[2][nt][0], sf[2][nt][1]),
                                 fmaxf(sf[2][nt][2], sf[2][nt][3]));
                float a3 = fmaxf(fmaxf(sf[3][nt][0], sf[3][nt][1]),
                                 fmaxf(sf[3][nt][2], sf[3][nt][3]));
                float t = fmaxf(fmaxf(a0, a1), fmaxf(a2, a3));
                t = fmaxf(t, __shfl_xor(t, 16, 64));
                t = fmaxf(t, __shfl_xor(t, 32, 64));
                tm[nt] = t;
            }
            const bool defer = __all(tm[0] <= mrow[0] + 8.0f) &&
                               __all(tm[1] <= mrow[1] + 8.0f);
            if (!defer) {
                float alpha[2];
                #pragma unroll
                for (int nt = 0; nt < 2; ++nt) {
                    float mn = fmaxf(mrow[nt], tm[nt]);
                    alpha[nt] = EXP2(mrow[nt] - mn);
                    mrow[nt] = mn;
                    lrow[nt] *= alpha[nt];
                }
                #pragma unroll
                for (int mt = 0; mt < 2; ++mt) {
                    #pragma unroll
                    for (int r = 0; r < 4; ++r) {
                        float ar = __shfl(alpha[mt], l4 * 4 + r, 64);
                        #pragma unroll
                        for (int nt = 0; nt < 8; ++nt) O[mt][nt][r] *= ar;
                    }
                }
            }
            // ---------- P in registers (bf16 pairs), per-column sums --------
            union PF { bf16x4 v; uint32_t u[2]; };
            PF pfrag[4][2];
            #pragma unroll
            for (int nt = 0; nt < 2; ++nt) {
                float me = fmaxf(mrow[nt], -1e20f);   // fully-masked rows -> p = 0
                float s[4];
                #pragma unroll
                for (int mt = 0; mt < 4; ++mt) {
                    float p0 = EXP2(sf[mt][nt][0] - me);
                    float p1 = EXP2(sf[mt][nt][1] - me);
                    float p2 = EXP2(sf[mt][nt][2] - me);
                    float p3 = EXP2(sf[mt][nt][3] - me);
                    pfrag[mt][nt].u[0] = pk2(p0, p1);
                    pfrag[mt][nt].u[1] = pk2(p2, p3);
                    s[mt] = (p0 + p1) + (p2 + p3);
                }
                float ts = (s[0] + s[1]) + (s[2] + s[3]);
                ts += __shfl_xor(ts, 16, 64);
                ts += __shfl_xor(ts, 32, 64);
                lrow[nt] += ts;
            }
            // ---- pack next tile into other buffer (overlaps with PV) -------
            if (more) pack(par ^ 1);
            // ---------- O += P · V  (K=16 MFMAs, A straight from regs) ------
            #pragma unroll
            for (int mt = 0; mt < 4; ++mt) {
                #pragma unroll
                for (int nt = 0; nt < 8; ++nt) {
                    bf16x4 vf = *reinterpret_cast<const bf16x4*>(
                        &lds_vt[par][(nt * 16 + l15) * VSTR + mt * 16 + l4 * 4]);
                    O[0][nt] = mfma16(pfrag[mt][0].v, vf, O[0][nt]);
                    O[1][nt] = mfma16(pfrag[mt][1].v, vf, O[1][nt]);
                }
            }
        } else {
            if (more) pack(par ^ 1);
        }
        __syncthreads();
        par ^= 1;
    }

    // ---------- epilogue: O / l, f32 out ----------
    #pragma unroll
    for (int mt = 0; mt < 2; ++mt) {
        float inv = 1.0f / lrow[mt];
        #pragma unroll
        for (int r = 0; r < 4; ++r) {
            float li = __shfl(inv, l4 * 4 + r, 64);
            int row = i0 + mt * 16 + l4 * 4 + r;
            float* orow = out + qbase + (size_t)row * HD;
            #pragma unroll
            for (int nt = 0; nt < 8; ++nt)
                orow[nt * 16 + l15] = O[mt][nt][r] * li;
        }
    }
}

extern "C" void kernel_launch(void* const* d_in, const int* in_sizes, int n_in,
                              void* d_out, int out_size, void* d_ws, size_t ws_size,
                              hipStream_t stream) {
    const float* q = (const float*)d_in[0];
    const float* k = (const float*)d_in[1];
    const float* v = (const float*)d_in[2];
    float* out     = (float*)d_out;

    hipLaunchKernelGGL(fa_mfma, dim3(BATCH * NH * (SEQ / 128)), dim3(256), 0, stream,
                       q, k, v, out);
}

// Round 3
// 176.107 us; speedup vs baseline: 1.0924x; 1.0924x over previous
//
#include <hip/hip_runtime.h>
#include <hip/hip_bf16.h>
#include <stdint.h>

#define SEQ 2048
#define HD  128
#define WIN 512
#define NH  16
#define NKV 4
#define BATCH 2

typedef __attribute__((ext_vector_type(8))) short bf16x8;
typedef __attribute__((ext_vector_type(4))) short bf16x4;
typedef __attribute__((ext_vector_type(4))) float f32x4;
typedef __attribute__((ext_vector_type(4))) uint32_t u32x4;
typedef __attribute__((ext_vector_type(2))) uint32_t u32x2;

// v_exp_f32: D = 2^S0 — avoids the glibc __exp2f macro collision
#define EXP2(x) __builtin_amdgcn_exp2f(x)

// LDS row strides in bf16 elements (byte-strides multiples of 16B for b128)
#define KSTR 136   // K tile  [64 keys][128 dims]
#define VSTR 72    // V^T tile [128 dims][64 keys]

__device__ __forceinline__ uint32_t pk2(float a, float b) {
    __hip_bfloat162 h = __float22bfloat162_rn(make_float2(a, b));
    return *reinterpret_cast<uint32_t*>(&h);
}

// K=16 MFMA: A-operand layout (row=lane&15, k=(lane>>4)*4+j) matches the
// 16x16 C-layout of S^T exactly -> P feeds PV directly from registers.
__device__ __forceinline__ f32x4 mfma16(bf16x4 a, bf16x4 b, f32x4 c) {
#if __has_builtin(__builtin_amdgcn_mfma_f32_16x16x16bf16_1k)
    return __builtin_amdgcn_mfma_f32_16x16x16bf16_1k(a, b, c, 0, 0, 0);
#else
    asm volatile("v_mfma_f32_16x16x16_bf16 %0, %1, %2, %0\n\ts_nop 7\n\ts_nop 7"
                 : "+v"(c) : "v"(a), "v"(b));
    return c;
#endif
}

// 4 waves/block, 32 queries/wave. S^T = K·Q^T so softmax stats are per-column
// (q = lane&15). K/V double-buffered in LDS -> single barrier per tile.
// P never touches LDS (16x16x16 PV straight from registers, bit_cast only —
// no memory-typed unions, so nothing can fall to scratch). pack_k right after
// QK^T and pack_v after softmax keep prefetch registers' live ranges short.
__global__ __launch_bounds__(256, 2) void fa_mfma(
    const float* __restrict__ q,
    const float* __restrict__ k,
    const float* __restrict__ v,
    float* __restrict__ out)
{
    const int tid  = threadIdx.x;
    const int wave = tid >> 6;
    const int lane = tid & 63;
    const int l4   = lane >> 4;
    const int l15  = lane & 15;

    const int bh   = blockIdx.x >> 4;      // b*NH + h
    const int qblk = blockIdx.x & 15;
    const int q0   = qblk << 7;            // 128 queries per block
    const int hkv  = (bh & (NH - 1)) >> 2; // G = 4
    const int b    = bh >> 4;

    const int i0   = q0 + wave * 32;       // wave's first query row

    __shared__ __align__(16) uint16_t lds_k[2][64 * KSTR];
    __shared__ __align__(16) uint16_t lds_vt[2][HD * VSTR];

    // scale * log2(e): softmax computed in exp2 domain
    const float scale2 = 0.08838834764831845f * 1.4426950408889634f;

    const size_t qbase  = (size_t)bh * SEQ * HD;
    const size_t kvbase = (size_t)(b * NKV + hkv) * SEQ * HD;

    // ---- preload Q fragments (B-operand: B[k=dim][n=q]) ----
    bf16x8 qf[2][4];
    #pragma unroll
    for (int nt = 0; nt < 2; ++nt) {
        const float* qr = q + qbase + (size_t)(i0 + nt * 16 + l15) * HD;
        #pragma unroll
        for (int ks = 0; ks < 4; ++ks) {
            const float4* g = reinterpret_cast<const float4*>(qr + ks * 32 + l4 * 8);
            float4 a = g[0], bq = g[1];
            u32x4 t;
            t.x = pk2(a.x * scale2, a.y * scale2);
            t.y = pk2(a.z * scale2, a.w * scale2);
            t.z = pk2(bq.x * scale2, bq.y * scale2);
            t.w = pk2(bq.z * scale2, bq.w * scale2);
            qf[nt][ks] = __builtin_bit_cast(bf16x8, t);
        }
    }

    f32x4 O[2][8];
    #pragma unroll
    for (int a1 = 0; a1 < 2; ++a1)
        #pragma unroll
        for (int a2 = 0; a2 < 8; ++a2) O[a1][a2] = (f32x4){0.f, 0.f, 0.f, 0.f};
    float mrow[2] = {-1e30f, -1e30f};
    float lrow[2] = {0.f, 0.f};

    const int kt_lo_blk = (q0 >= 512) ? ((q0 - 511) >> 6) : 0;
    const int kt_hi_blk = (q0 + 127) >> 6;
    const int lo_w = (i0 >= 512) ? ((i0 - 511) >> 6) : 0;
    const int hi_w = (i0 + 31) >> 6;

    // ---- prefetch registers ----
    const int vdg = tid & 31;   // dim group (4 dims)
    const int vkg = tid >> 5;   // key group (8 keys)
    float4 rKa[4], rKb[4], rV[8];

    auto prefetch = [&](int kt) {
        const float* kp = k + kvbase + (size_t)kt * 64 * HD;
        const float* vp = v + kvbase + (size_t)kt * 64 * HD;
        #pragma unroll
        for (int it = 0; it < 4; ++it) {
            int flat8 = tid + it * 256, key = flat8 >> 4, ch = flat8 & 15;
            const float4* g = reinterpret_cast<const float4*>(kp + key * HD + ch * 8);
            rKa[it] = g[0]; rKb[it] = g[1];
        }
        #pragma unroll
        for (int r = 0; r < 8; ++r)
            rV[r] = *reinterpret_cast<const float4*>(vp + (vkg * 8 + r) * HD + vdg * 4);
    };

    auto pack_k = [&](int pb) {
        #pragma unroll
        for (int it = 0; it < 4; ++it) {
            int flat8 = tid + it * 256, key = flat8 >> 4, ch = flat8 & 15;
            uint4 wv;
            wv.x = pk2(rKa[it].x, rKa[it].y);  wv.y = pk2(rKa[it].z, rKa[it].w);
            wv.z = pk2(rKb[it].x, rKb[it].y);  wv.w = pk2(rKb[it].z, rKb[it].w);
            *reinterpret_cast<uint4*>(&lds_k[pb][key * KSTR + ch * 8]) = wv;
        }
    };
    auto pack_v = [&](int pb) {
        // V (register 8x4 transpose) -> LDS
        const float* rvf = reinterpret_cast<const float*>(rV);
        #pragma unroll
        for (int i = 0; i < 4; ++i) {
            uint4 wv;
            wv.x = pk2(rvf[0 * 4 + i], rvf[1 * 4 + i]);
            wv.y = pk2(rvf[2 * 4 + i], rvf[3 * 4 + i]);
            wv.z = pk2(rvf[4 * 4 + i], rvf[5 * 4 + i]);
            wv.w = pk2(rvf[6 * 4 + i], rvf[7 * 4 + i]);
            *reinterpret_cast<uint4*>(&lds_vt[pb][(vdg * 4 + i) * VSTR + vkg * 8]) = wv;
        }
    };

    prefetch(kt_lo_blk);
    pack_k(0);
    pack_v(0);
    __syncthreads();

    int par = 0;
    for (int kt = kt_lo_blk; kt <= kt_hi_blk; ++kt) {
        const bool more = (kt < kt_hi_blk);
        if (more) prefetch(kt + 1);   // issue next tile's global loads early

        if (kt >= lo_w && kt <= hi_w) {
            // ---------- S^T = K · Q^T ----------
            f32x4 sf[4][2];
            #pragma unroll
            for (int mt = 0; mt < 4; ++mt) {
                #pragma unroll
                for (int nt = 0; nt < 2; ++nt) sf[mt][nt] = (f32x4){0.f, 0.f, 0.f, 0.f};
                #pragma unroll
                for (int ks = 0; ks < 4; ++ks) {
                    bf16x8 af = *reinterpret_cast<const bf16x8*>(
                        &lds_k[par][(mt * 16 + l15) * KSTR + ks * 32 + l4 * 8]);
                    #pragma unroll
                    for (int nt = 0; nt < 2; ++nt)
                        sf[mt][nt] = __builtin_amdgcn_mfma_f32_16x16x32_bf16(
                            af, qf[nt][ks], sf[mt][nt], 0, 0, 0);
                }
            }
            // ---- pack next K tile now: frees rKa/rKb, QK^T covered latency --
            if (more) pack_k(par ^ 1);
            // ---------- mask (first/window and last/causal tiles only) ------
            const bool needmask = (kt == hi_w) || (kt == lo_w && i0 > 511);
            if (needmask) {
                #pragma unroll
                for (int mt = 0; mt < 4; ++mt) {
                    int jb = kt * 64 + mt * 16 + l4 * 4;
                    #pragma unroll
                    for (int nt = 0; nt < 2; ++nt) {
                        int iq = i0 + nt * 16 + l15;
                        #pragma unroll
                        for (int r = 0; r < 4; ++r) {
                            int j = jb + r;
                            if (!((j <= iq) && (iq - j < WIN))) sf[mt][nt][r] = -1e30f;
                        }
                    }
                }
            }
            // ---------- online softmax, exp2 domain, defer-max (THR=8) ------
            float tm[2];
            #pragma unroll
            for (int nt = 0; nt < 2; ++nt) {
                float a0 = fmaxf(fmaxf(sf[0][nt][0], sf[0][nt][1]),
                                 fmaxf(sf[0][nt][2], sf[0][nt][3]));
                float a1 = fmaxf(fmaxf(sf[1][nt][0], sf[1][nt][1]),
                                 fmaxf(sf[1][nt][2], sf[1][nt][3]));
                float a2 = fmaxf(fmaxf(sf[2][nt][0], sf[2][nt][1]),
                                 fmaxf(sf[2][nt][2], sf[2][nt][3]));
                float a3 = fmaxf(fmaxf(sf[3][nt][0], sf[3][nt][1]),
                                 fmaxf(sf[3][nt][2], sf[3][nt][3]));
                float t = fmaxf(fmaxf(a0, a1), fmaxf(a2, a3));
                t = fmaxf(t, __shfl_xor(t, 16, 64));
                t = fmaxf(t, __shfl_xor(t, 32, 64));
                tm[nt] = t;
            }
            const bool defer = __all(tm[0] <= mrow[0] + 8.0f) &&
                               __all(tm[1] <= mrow[1] + 8.0f);
            if (!defer) {
                float alpha[2];
                #pragma unroll
                for (int nt = 0; nt < 2; ++nt) {
                    float mn = fmaxf(mrow[nt], tm[nt]);
                    alpha[nt] = EXP2(mrow[nt] - mn);
                    mrow[nt] = mn;
                    lrow[nt] *= alpha[nt];
                }
                #pragma unroll
                for (int mt = 0; mt < 2; ++mt) {
                    #pragma unroll
                    for (int r = 0; r < 4; ++r) {
                        float ar = __shfl(alpha[mt], l4 * 4 + r, 64);
                        #pragma unroll
                        for (int nt = 0; nt < 8; ++nt) O[mt][nt][r] *= ar;
                    }
                }
            }
            // ---------- P in registers (bf16 pairs), per-column sums --------
            bf16x4 pfrag[4][2];
            #pragma unroll
            for (int nt = 0; nt < 2; ++nt) {
                float me = fmaxf(mrow[nt], -1e20f);   // fully-masked rows -> p = 0
                float s[4];
                #pragma unroll
                for (int mt = 0; mt < 4; ++mt) {
                    float p0 = EXP2(sf[mt][nt][0] - me);
                    float p1 = EXP2(sf[mt][nt][1] - me);
                    float p2 = EXP2(sf[mt][nt][2] - me);
                    float p3 = EXP2(sf[mt][nt][3] - me);
                    u32x2 t;
                    t.x = pk2(p0, p1);
                    t.y = pk2(p2, p3);
                    pfrag[mt][nt] = __builtin_bit_cast(bf16x4, t);
                    s[mt] = (p0 + p1) + (p2 + p3);
                }
                float ts = (s[0] + s[1]) + (s[2] + s[3]);
                ts += __shfl_xor(ts, 16, 64);
                ts += __shfl_xor(ts, 32, 64);
                lrow[nt] += ts;
            }
            // ---- pack next V tile (frees rV; overlaps with PV issue) -------
            if (more) pack_v(par ^ 1);
            // ---------- O += P · V  (K=16 MFMAs, A straight from regs) ------
            #pragma unroll
            for (int mt = 0; mt < 4; ++mt) {
                #pragma unroll
                for (int nt = 0; nt < 8; ++nt) {
                    bf16x4 vf = *reinterpret_cast<const bf16x4*>(
                        &lds_vt[par][(nt * 16 + l15) * VSTR + mt * 16 + l4 * 4]);
                    O[0][nt] = mfma16(pfrag[mt][0], vf, O[0][nt]);
                    O[1][nt] = mfma16(pfrag[mt][1], vf, O[1][nt]);
                }
            }
        } else {
            if (more) { pack_k(par ^ 1); pack_v(par ^ 1); }
        }
        __syncthreads();
        par ^= 1;
    }

    // ---------- epilogue: O / l, f32 out ----------
    #pragma unroll
    for (int mt = 0; mt < 2; ++mt) {
        float inv = 1.0f / lrow[mt];
        #pragma unroll
        for (int r = 0; r < 4; ++r) {
            float li = __shfl(inv, l4 * 4 + r, 64);
            int row = i0 + mt * 16 + l4 * 4 + r;
            float* orow = out + qbase + (size_t)row * HD;
            #pragma unroll
            for (int nt = 0; nt < 8; ++nt)
                orow[nt * 16 + l15] = O[mt][nt][r] * li;
        }
    }
}

extern "C" void kernel_launch(void* const* d_in, const int* in_sizes, int n_in,
                              void* d_out, int out_size, void* d_ws, size_t ws_size,
                              hipStream_t stream) {
    const float* q = (const float*)d_in[0];
    const float* k = (const float*)d_in[1];
    const float* v = (const float*)d_in[2];
    float* out     = (float*)d_out;

    hipLaunchKernelGGL(fa_mfma, dim3(BATCH * NH * (SEQ / 128)), dim3(256), 0, stream,
                       q, k, v, out);
}

// Round 4
// 139.263 us; speedup vs baseline: 1.3813x; 1.2646x over previous
//
#include <hip/hip_runtime.h>
#include <hip/hip_bf16.h>
#include <stdint.h>

#define SEQ 2048
#define HD  128
#define WIN 512
#define NH  16
#define NKV 4
#define BATCH 2

typedef __attribute__((ext_vector_type(8))) short bf16x8;
typedef __attribute__((ext_vector_type(4))) short bf16x4;
typedef __attribute__((ext_vector_type(4))) float f32x4;
typedef __attribute__((ext_vector_type(4))) uint32_t u32x4;
typedef __attribute__((ext_vector_type(2))) uint32_t u32x2;

// v_exp_f32: D = 2^S0 — avoids the glibc __exp2f macro collision
#define EXP2(x) __builtin_amdgcn_exp2f(x)

// LDS row strides in bf16 elements (byte-strides multiples of 16B for b128)
#define KSTR 136   // K tile  [64 keys][128 dims]
#define VSTR 72    // V^T tile [128 dims][64 keys]

__device__ __forceinline__ uint32_t pk2(float a, float b) {
    __hip_bfloat162 h = __float22bfloat162_rn(make_float2(a, b));
    return *reinterpret_cast<uint32_t*>(&h);
}

// K=16 MFMA: A-operand layout (row=lane&15, k=(lane>>4)*4+j) matches the
// 16x16 C-layout of S^T exactly -> P feeds PV directly from registers.
__device__ __forceinline__ f32x4 mfma16(bf16x4 a, bf16x4 b, f32x4 c) {
#if __has_builtin(__builtin_amdgcn_mfma_f32_16x16x16bf16_1k)
    return __builtin_amdgcn_mfma_f32_16x16x16bf16_1k(a, b, c, 0, 0, 0);
#else
    asm volatile("v_mfma_f32_16x16x16_bf16 %0, %1, %2, %0\n\ts_nop 7\n\ts_nop 7"
                 : "+v"(c) : "v"(a), "v"(b));
    return c;
#endif
}

// 4 waves/block, 32 queries/wave. S^T = K·Q^T so softmax stats are per-column
// (q = lane&15). K/V double-buffered in LDS -> single barrier per tile.
// P never touches LDS (16x16x16 PV straight from registers).
//
// Occupancy is LDS-capped at 2 blocks/CU (71680 B), so pin the register
// budget to match: waves_per_eu(2,2) -> 256-VGPR budget. Without it the
// backend targeted 4 waves/EU (128 VGPRs) and spilled ~70 MB/dispatch of
// scratch to HBM (rounds 1/3: WRITE_SIZE 150/101 MB vs 33 MB ideal).
__global__ __launch_bounds__(256) __attribute__((amdgpu_waves_per_eu(2, 2)))
void fa_mfma(
    const float* __restrict__ q,
    const float* __restrict__ k,
    const float* __restrict__ v,
    float* __restrict__ out)
{
    const int tid  = threadIdx.x;
    const int wave = tid >> 6;
    const int lane = tid & 63;
    const int l4   = lane >> 4;
    const int l15  = lane & 15;

    const int bh   = blockIdx.x >> 4;      // b*NH + h
    const int qblk = blockIdx.x & 15;
    const int q0   = qblk << 7;            // 128 queries per block
    const int hkv  = (bh & (NH - 1)) >> 2; // G = 4
    const int b    = bh >> 4;

    const int i0   = q0 + wave * 32;       // wave's first query row

    __shared__ __align__(16) uint16_t lds_k[2][64 * KSTR];
    __shared__ __align__(16) uint16_t lds_vt[2][HD * VSTR];

    // scale * log2(e): softmax computed in exp2 domain
    const float scale2 = 0.08838834764831845f * 1.4426950408889634f;

    const size_t qbase  = (size_t)bh * SEQ * HD;
    const size_t kvbase = (size_t)(b * NKV + hkv) * SEQ * HD;

    // ---- preload Q fragments (B-operand: B[k=dim][n=q]) ----
    bf16x8 qf[2][4];
    #pragma unroll
    for (int nt = 0; nt < 2; ++nt) {
        const float* qr = q + qbase + (size_t)(i0 + nt * 16 + l15) * HD;
        #pragma unroll
        for (int ks = 0; ks < 4; ++ks) {
            const float4* g = reinterpret_cast<const float4*>(qr + ks * 32 + l4 * 8);
            float4 a = g[0], bq = g[1];
            u32x4 t;
            t.x = pk2(a.x * scale2, a.y * scale2);
            t.y = pk2(a.z * scale2, a.w * scale2);
            t.z = pk2(bq.x * scale2, bq.y * scale2);
            t.w = pk2(bq.z * scale2, bq.w * scale2);
            qf[nt][ks] = __builtin_bit_cast(bf16x8, t);
        }
    }

    f32x4 O[2][8];
    #pragma unroll
    for (int a1 = 0; a1 < 2; ++a1)
        #pragma unroll
        for (int a2 = 0; a2 < 8; ++a2) O[a1][a2] = (f32x4){0.f, 0.f, 0.f, 0.f};
    float mrow[2] = {-1e30f, -1e30f};
    float lrow[2] = {0.f, 0.f};

    const int kt_lo_blk = (q0 >= 512) ? ((q0 - 511) >> 6) : 0;
    const int kt_hi_blk = (q0 + 127) >> 6;
    const int lo_w = (i0 >= 512) ? ((i0 - 511) >> 6) : 0;
    const int hi_w = (i0 + 31) >> 6;

    // ---- prefetch registers ----
    const int vdg = tid & 31;   // dim group (4 dims)
    const int vkg = tid >> 5;   // key group (8 keys)
    float4 rKa[4], rKb[4], rV[8];

    auto prefetch_k = [&](int kt) {
        const float* kp = k + kvbase + (size_t)kt * 64 * HD;
        #pragma unroll
        for (int it = 0; it < 4; ++it) {
            int flat8 = tid + it * 256, key = flat8 >> 4, ch = flat8 & 15;
            const float4* g = reinterpret_cast<const float4*>(kp + key * HD + ch * 8);
            rKa[it] = g[0]; rKb[it] = g[1];
        }
    };
    auto prefetch_v = [&](int kt) {
        const float* vp = v + kvbase + (size_t)kt * 64 * HD;
        #pragma unroll
        for (int r = 0; r < 8; ++r)
            rV[r] = *reinterpret_cast<const float4*>(vp + (vkg * 8 + r) * HD + vdg * 4);
    };

    auto pack_k = [&](int pb) {
        #pragma unroll
        for (int it = 0; it < 4; ++it) {
            int flat8 = tid + it * 256, key = flat8 >> 4, ch = flat8 & 15;
            uint4 wv;
            wv.x = pk2(rKa[it].x, rKa[it].y);  wv.y = pk2(rKa[it].z, rKa[it].w);
            wv.z = pk2(rKb[it].x, rKb[it].y);  wv.w = pk2(rKb[it].z, rKb[it].w);
            *reinterpret_cast<uint4*>(&lds_k[pb][key * KSTR + ch * 8]) = wv;
        }
    };
    auto pack_v = [&](int pb) {
        // V (register 8x4 transpose) -> LDS
        const float* rvf = reinterpret_cast<const float*>(rV);
        #pragma unroll
        for (int i = 0; i < 4; ++i) {
            uint4 wv;
            wv.x = pk2(rvf[0 * 4 + i], rvf[1 * 4 + i]);
            wv.y = pk2(rvf[2 * 4 + i], rvf[3 * 4 + i]);
            wv.z = pk2(rvf[4 * 4 + i], rvf[5 * 4 + i]);
            wv.w = pk2(rvf[6 * 4 + i], rvf[7 * 4 + i]);
            *reinterpret_cast<uint4*>(&lds_vt[pb][(vdg * 4 + i) * VSTR + vkg * 8]) = wv;
        }
    };

    prefetch_k(kt_lo_blk);
    prefetch_v(kt_lo_blk);
    pack_k(0);
    pack_v(0);
    __syncthreads();

    int par = 0;
    for (int kt = kt_lo_blk; kt <= kt_hi_blk; ++kt) {
        const bool more = (kt < kt_hi_blk);
        if (more) prefetch_k(kt + 1);   // K loads early; V loads after pack_k

        if (kt >= lo_w && kt <= hi_w) {
            // ---------- S^T = K · Q^T ----------
            f32x4 sf[4][2];
            #pragma unroll
            for (int mt = 0; mt < 4; ++mt) {
                #pragma unroll
                for (int nt = 0; nt < 2; ++nt) sf[mt][nt] = (f32x4){0.f, 0.f, 0.f, 0.f};
                #pragma unroll
                for (int ks = 0; ks < 4; ++ks) {
                    bf16x8 af = *reinterpret_cast<const bf16x8*>(
                        &lds_k[par][(mt * 16 + l15) * KSTR + ks * 32 + l4 * 8]);
                    #pragma unroll
                    for (int nt = 0; nt < 2; ++nt)
                        sf[mt][nt] = __builtin_amdgcn_mfma_f32_16x16x32_bf16(
                            af, qf[nt][ks], sf[mt][nt], 0, 0, 0);
                }
            }
            // ---- pack next K tile (frees rKa/rKb), then issue V loads ------
            if (more) { pack_k(par ^ 1); prefetch_v(kt + 1); }
            // ---------- mask (first/window and last/causal tiles only) ------
            const bool needmask = (kt == hi_w) || (kt == lo_w && i0 > 511);
            if (needmask) {
                #pragma unroll
                for (int mt = 0; mt < 4; ++mt) {
                    int jb = kt * 64 + mt * 16 + l4 * 4;
                    #pragma unroll
                    for (int nt = 0; nt < 2; ++nt) {
                        int iq = i0 + nt * 16 + l15;
                        #pragma unroll
                        for (int r = 0; r < 4; ++r) {
                            int j = jb + r;
                            if (!((j <= iq) && (iq - j < WIN))) sf[mt][nt][r] = -1e30f;
                        }
                    }
                }
            }
            // ---------- online softmax, exp2 domain, defer-max (THR=8) ------
            float tm[2];
            #pragma unroll
            for (int nt = 0; nt < 2; ++nt) {
                float a0 = fmaxf(fmaxf(sf[0][nt][0], sf[0][nt][1]),
                                 fmaxf(sf[0][nt][2], sf[0][nt][3]));
                float a1 = fmaxf(fmaxf(sf[1][nt][0], sf[1][nt][1]),
                                 fmaxf(sf[1][nt][2], sf[1][nt][3]));
                float a2 = fmaxf(fmaxf(sf[2][nt][0], sf[2][nt][1]),
                                 fmaxf(sf[2][nt][2], sf[2][nt][3]));
                float a3 = fmaxf(fmaxf(sf[3][nt][0], sf[3][nt][1]),
                                 fmaxf(sf[3][nt][2], sf[3][nt][3]));
                float t = fmaxf(fmaxf(a0, a1), fmaxf(a2, a3));
                t = fmaxf(t, __shfl_xor(t, 16, 64));
                t = fmaxf(t, __shfl_xor(t, 32, 64));
                tm[nt] = t;
            }
            const bool defer = __all(tm[0] <= mrow[0] + 8.0f) &&
                               __all(tm[1] <= mrow[1] + 8.0f);
            if (!defer) {
                float alpha[2];
                #pragma unroll
                for (int nt = 0; nt < 2; ++nt) {
                    float mn = fmaxf(mrow[nt], tm[nt]);
                    alpha[nt] = EXP2(mrow[nt] - mn);
                    mrow[nt] = mn;
                    lrow[nt] *= alpha[nt];
                }
                #pragma unroll
                for (int mt = 0; mt < 2; ++mt) {
                    #pragma unroll
                    for (int r = 0; r < 4; ++r) {
                        float ar = __shfl(alpha[mt], l4 * 4 + r, 64);
                        #pragma unroll
                        for (int nt = 0; nt < 8; ++nt) O[mt][nt][r] *= ar;
                    }
                }
            }
            // ---------- P in registers (bf16 pairs), per-column sums --------
            bf16x4 pfrag[4][2];
            #pragma unroll
            for (int nt = 0; nt < 2; ++nt) {
                float me = fmaxf(mrow[nt], -1e20f);   // fully-masked rows -> p = 0
                float s[4];
                #pragma unroll
                for (int mt = 0; mt < 4; ++mt) {
                    float p0 = EXP2(sf[mt][nt][0] - me);
                    float p1 = EXP2(sf[mt][nt][1] - me);
                    float p2 = EXP2(sf[mt][nt][2] - me);
                    float p3 = EXP2(sf[mt][nt][3] - me);
                    u32x2 t;
                    t.x = pk2(p0, p1);
                    t.y = pk2(p2, p3);
                    pfrag[mt][nt] = __builtin_bit_cast(bf16x4, t);
                    s[mt] = (p0 + p1) + (p2 + p3);
                }
                float ts = (s[0] + s[1]) + (s[2] + s[3]);
                ts += __shfl_xor(ts, 16, 64);
                ts += __shfl_xor(ts, 32, 64);
                lrow[nt] += ts;
            }
            // ---- pack next V tile (frees rV; overlaps with PV issue) -------
            if (more) pack_v(par ^ 1);
            // ---------- O += P · V  (K=16 MFMAs, A straight from regs) ------
            #pragma unroll
            for (int mt = 0; mt < 4; ++mt) {
                #pragma unroll
                for (int nt = 0; nt < 8; ++nt) {
                    bf16x4 vf = *reinterpret_cast<const bf16x4*>(
                        &lds_vt[par][(nt * 16 + l15) * VSTR + mt * 16 + l4 * 4]);
                    O[0][nt] = mfma16(pfrag[mt][0], vf, O[0][nt]);
                    O[1][nt] = mfma16(pfrag[mt][1], vf, O[1][nt]);
                }
            }
        } else {
            if (more) { prefetch_v(kt + 1); pack_k(par ^ 1); pack_v(par ^ 1); }
        }
        __syncthreads();
        par ^= 1;
    }

    // ---------- epilogue: O / l, f32 out ----------
    #pragma unroll
    for (int mt = 0; mt < 2; ++mt) {
        float inv = 1.0f / lrow[mt];
        #pragma unroll
        for (int r = 0; r < 4; ++r) {
            float li = __shfl(inv, l4 * 4 + r, 64);
            int row = i0 + mt * 16 + l4 * 4 + r;
            float* orow = out + qbase + (size_t)row * HD;
            #pragma unroll
            for (int nt = 0; nt < 8; ++nt)
                orow[nt * 16 + l15] = O[mt][nt][r] * li;
        }
    }
}

extern "C" void kernel_launch(void* const* d_in, const int* in_sizes, int n_in,
                              void* d_out, int out_size, void* d_ws, size_t ws_size,
                              hipStream_t stream) {
    const float* q = (const float*)d_in[0];
    const float* k = (const float*)d_in[1];
    const float* v = (const float*)d_in[2];
    float* out     = (float*)d_out;

    hipLaunchKernelGGL(fa_mfma, dim3(BATCH * NH * (SEQ / 128)), dim3(256), 0, stream,
                       q, k, v, out);
}